// Round 6
// baseline (163.410 us; speedup 1.0000x reference)
//
#include <hip/hip_runtime.h>

typedef float  f32x4  __attribute__((ext_vector_type(4)));
typedef short  bf16x8 __attribute__((ext_vector_type(8)));

#define NN 2048
#define CC 64

#define WAITVM(N) asm volatile("s_waitcnt vmcnt(" #N ")" ::: "memory")
#define LGKM0     asm volatile("s_waitcnt lgkmcnt(0)" ::: "memory")

__device__ __forceinline__ unsigned short f2bf(float f) {
  union { float f; unsigned u; } v; v.f = f;
  unsigned r = v.u + 0x7fffu + ((v.u >> 16) & 1u);
  return (unsigned short)(r >> 16);
}

__device__ __forceinline__ void gll16(const void* g, void* l) {
  __builtin_amdgcn_global_load_lds(
      (const __attribute__((address_space(1))) unsigned int*)g,
      (__attribute__((address_space(3))) unsigned int*)l, 16, 0, 0);
}

// ---------- pure-stream A conversion: fp32 -> bf16, gemm-tiled layout ----------
// Same (bid,w,lane) geometry as the gemm: wgid=bid*8+w owns a 16-row x 256-col panel.
// Abf[wgid*4096 + t*1024 + h*512 + lane*8 + j] = bf16(A[b][n0+fr][j0 + t*64 + h*32 + g*8 + j])
__global__ __launch_bounds__(512) void convA(
    const float* __restrict__ A, unsigned short* __restrict__ Abf)
{
  const int bid = blockIdx.x;
  const int b   = bid & 7;
  const int n0  = (bid >> 3) << 4;
  const int tid = threadIdx.x;
  const int w   = tid >> 6, lane = tid & 63;
  const int fr  = lane & 15, g = lane >> 4;
  const int j0  = w << 8;

  const float* src = A + ((size_t)b * NN + (n0 + fr)) * NN + j0 + (g << 3);
  unsigned short* dst = Abf + ((size_t)bid * 8 + w) * 4096 + lane * 8;

#pragma unroll
  for (int t = 0; t < 4; ++t)
#pragma unroll
    for (int h = 0; h < 2; ++h) {
      float4 lo = *reinterpret_cast<const float4*>(src + t * 64 + h * 32);
      float4 hi = *reinterpret_cast<const float4*>(src + t * 64 + h * 32 + 4);
      bf16x8 pk;
      pk[0] = (short)f2bf(lo.x); pk[1] = (short)f2bf(lo.y);
      pk[2] = (short)f2bf(lo.z); pk[3] = (short)f2bf(lo.w);
      pk[4] = (short)f2bf(hi.x); pk[5] = (short)f2bf(hi.y);
      pk[6] = (short)f2bf(hi.z); pk[7] = (short)f2bf(hi.w);
      *reinterpret_cast<bf16x8*>(dst + t * 1024 + h * 512) = pk;
    }
}

// ---------------- per-layer linear: Mt = (H*Wm^T)^T bf16, S = H*Ws^T + b ----------------
__global__ __launch_bounds__(256) void gcn_linear(
    const float* __restrict__ H, const float* __restrict__ Wm,
    const float* __restrict__ Ws, const float* __restrict__ bias,
    unsigned short* __restrict__ Mt, float* __restrict__ S)
{
  const int bid = blockIdx.x;
  const int b   = bid >> 5;
  const int n0  = (bid & 31) << 6;
  const int tid = threadIdx.x;

  __shared__ float4 Hl[1024];
  __shared__ float4 Wm4[1024];
  __shared__ float4 Ws4[1024];

  const float4* Hg  = reinterpret_cast<const float4*>(H + ((size_t)b * NN + n0) * CC);
  const float4* Wmg = reinterpret_cast<const float4*>(Wm);
  const float4* Wsg = reinterpret_cast<const float4*>(Ws);
#pragma unroll
  for (int i = 0; i < 4; ++i) {
    int f = tid + 256 * i;
    Hl[f] = Hg[f];
    int o = f >> 4, c4 = f & 15;
    int slot = (o << 4) | (c4 ^ (o & 15));
    Wm4[slot] = Wmg[f];
    Ws4[slot] = Wsg[f];
  }
  __syncthreads();

  const int o = tid & 63, wv = tid >> 6;
  float accm[16], accs[16];
#pragma unroll
  for (int p = 0; p < 16; ++p) { accm[p] = 0.f; accs[p] = 0.f; }

  for (int c4 = 0; c4 < 16; ++c4) {
    int slot = (o << 4) | (c4 ^ (o & 15));
    float4 wm  = Wm4[slot];
    float4 wsv = Ws4[slot];
#pragma unroll
    for (int p = 0; p < 16; ++p) {
      float4 h = Hl[((wv << 4) + p) * 16 + c4];
      accm[p] += h.x * wm.x  + h.y * wm.y  + h.z * wm.z  + h.w * wm.w;
      accs[p] += h.x * wsv.x + h.y * wsv.y + h.z * wsv.z + h.w * wsv.w;
    }
  }

  const float bv = bias[o];
  // Mt store: 16 consecutive r at fixed o -> two 16B packed stores
  bf16x8 m0, m1;
#pragma unroll
  for (int p = 0; p < 8; ++p) { m0[p] = (short)f2bf(accm[p]); m1[p] = (short)f2bf(accm[8 + p]); }
  unsigned short* mp = Mt + ((size_t)b * CC + o) * NN + n0 + (wv << 4);
  *reinterpret_cast<bf16x8*>(mp)     = m0;
  *reinterpret_cast<bf16x8*>(mp + 8) = m1;
#pragma unroll
  for (int p = 0; p < 16; ++p) {
    int r = n0 + (wv << 4) + p;
    S[((size_t)b * NN + r) * CC + o] = accs[p] + bv;
  }
}

// ---------------- GEMM: H = relu?(A @ M + S) ----------------
// block = 16 rows x 8 waves; wave w owns j-chunk [w*256,+256), 4 K-tiles; per-wave
// private LDS ring depth-2 via global_load_lds, counted vmcnt only (no barriers in loop).
// DT=1: bf16 tiled Abf.  DT=2: fp32 A direct (fallback, no side-store).
template<int DT>
__global__ __launch_bounds__(512) void gcn_gemm(
    const float* __restrict__ A, const unsigned short* __restrict__ Abf,
    const unsigned short* __restrict__ Mt, const float* __restrict__ S,
    float* __restrict__ H, const int relu)
{
  constexpr int TILEB = (DT == 1) ? 2048 : 4096;
  __shared__ char smem[(DT == 1) ? 32768 : 65536];

  const int bid = blockIdx.x;
  const int b   = bid & 7;
  const int rb  = bid >> 3;
  const int n0  = rb << 4;
  const int tid  = threadIdx.x;
  const int w    = tid >> 6;
  const int lane = tid & 63;
  const int fr   = lane & 15, g = lane >> 4;
  const int j0   = w << 8;

  char* ring = smem + w * 2 * TILEB;

  const float* Ag = A + ((size_t)(b * NN + n0)) * NN + j0;
  const size_t wgid = (size_t)bid * 8 + w;
  const unsigned short* Mb = Mt + ((size_t)b * CC + fr) * NN + j0 + (g << 3);

  auto issueA = [&](int t, int s) {
    if constexpr (DT == 1) {
      const unsigned short* src = Abf + wgid * 4096 + (size_t)t * 1024 + lane * 8;
      gll16(src,       ring + s * TILEB);
      gll16(src + 512, ring + s * TILEB + 1024);
    } else {
      const int rl = lane >> 4, cl = lane & 15;
#pragma unroll
      for (int q = 0; q < 4; ++q) {
        int row = (q << 2) + rl;
        int c16 = cl ^ (row & 7);
        gll16(Ag + (size_t)row * NN + t * 64 + c16 * 4,
              ring + s * TILEB + (q << 10));
      }
    }
  };

  auto loadB = [&](bf16x8* Bv, int t) {
#pragma unroll
    for (int kk = 0; kk < 2; ++kk)
#pragma unroll
      for (int n = 0; n < 4; ++n)
        Bv[kk * 4 + n] = *reinterpret_cast<const bf16x8*>(
            Mb + (size_t)(n << 4) * NN + t * 64 + (kk << 5));
  };

  auto readA = [&](int s, bf16x8* af) {
    if constexpr (DT == 1) {
      af[0] = *reinterpret_cast<const bf16x8*>(ring + s * TILEB + lane * 16);
      af[1] = *reinterpret_cast<const bf16x8*>(ring + s * TILEB + 1024 + lane * 16);
      LGKM0;
    } else {
      const float4* sh = reinterpret_cast<const float4*>(ring + s * TILEB);
      float4 v[4];
#pragma unroll
      for (int kk = 0; kk < 2; ++kk) {
        v[2 * kk]     = sh[(fr << 4) + (((kk << 3) + (g << 1))     ^ (fr & 7))];
        v[2 * kk + 1] = sh[(fr << 4) + (((kk << 3) + (g << 1) + 1) ^ (fr & 7))];
      }
      LGKM0;
#pragma unroll
      for (int kk = 0; kk < 2; ++kk) {
        af[kk][0] = (short)f2bf(v[2 * kk].x);     af[kk][1] = (short)f2bf(v[2 * kk].y);
        af[kk][2] = (short)f2bf(v[2 * kk].z);     af[kk][3] = (short)f2bf(v[2 * kk].w);
        af[kk][4] = (short)f2bf(v[2 * kk + 1].x); af[kk][5] = (short)f2bf(v[2 * kk + 1].y);
        af[kk][6] = (short)f2bf(v[2 * kk + 1].z); af[kk][7] = (short)f2bf(v[2 * kk + 1].w);
      }
    }
  };

  f32x4 acc[4];
#pragma unroll
  for (int n = 0; n < 4; ++n) acc[n] = (f32x4){0.f, 0.f, 0.f, 0.f};

  auto mfma8 = [&](bf16x8* af, bf16x8* Bv) {
#pragma unroll
    for (int kk = 0; kk < 2; ++kk)
#pragma unroll
      for (int n = 0; n < 4; ++n)
        acc[n] = __builtin_amdgcn_mfma_f32_16x16x32_bf16(af[kk], Bv[kk * 4 + n], acc[n], 0, 0, 0);
  };

  bf16x8 B0[8], B1[8], B2[8], B3[8], af[2];

  loadB(B0, 0);
  issueA(0, 0); issueA(1, 1);

  if constexpr (DT == 1) { WAITVM(2); } else { WAITVM(4); }
  readA(0, af); loadB(B1, 1); issueA(2, 0); mfma8(af, B0);

  if constexpr (DT == 1) { WAITVM(10); } else { WAITVM(12); }
  readA(1, af); loadB(B2, 2); issueA(3, 1); mfma8(af, B1);

  if constexpr (DT == 1) { WAITVM(10); } else { WAITVM(12); }
  readA(0, af); loadB(B3, 3); mfma8(af, B2);

  if constexpr (DT == 1) { WAITVM(8); } else { WAITVM(10); }
  readA(1, af); mfma8(af, B3);

  // ---- cross-wave reduction (alias ring memory; all gll drained) ----
  __syncthreads();
  float* red = reinterpret_cast<float*>(smem);   // [8 waves][16 rows][64 cols]
#pragma unroll
  for (int n = 0; n < 4; ++n)
#pragma unroll
    for (int r = 0; r < 4; ++r)
      red[(w << 10) + (((g << 2) + r) << 6) + (n << 4) + fr] = acc[n][r];
  __syncthreads();
  {
    const int row = tid >> 5;
    const int col = (tid & 31) << 1;
    float2 v = make_float2(0.f, 0.f);
#pragma unroll
    for (int ww = 0; ww < 8; ++ww) {
      float2 p = *reinterpret_cast<const float2*>(&red[(ww << 10) + (row << 6) + col]);
      v.x += p.x; v.y += p.y;
    }
    const size_t idx = ((size_t)b * NN + n0 + row) * CC + col;
    float2 s = *reinterpret_cast<const float2*>(&S[idx]);
    v.x += s.x; v.y += s.y;
    if (relu) { v.x = fmaxf(v.x, 0.f); v.y = fmaxf(v.y, 0.f); }
    *reinterpret_cast<float2*>(&H[idx]) = v;
  }
}

extern "C" void kernel_launch(void* const* d_in, const int* in_sizes, int n_in,
                              void* d_out, int out_size, void* d_ws, size_t ws_size,
                              hipStream_t stream)
{
  const float* X = (const float*)d_in[0];
  const float* A = (const float*)d_in[1];
  const size_t MB = 1024 * 1024;
  unsigned short* Mt  = (unsigned short*)d_ws;                      // 2 MiB
  float*          S   = (float*)((char*)d_ws + 2 * MB);             // 4 MiB
  unsigned short* Abf = (unsigned short*)((char*)d_ws + 6 * MB);    // 64 MiB tiled bf16 A
  const bool has_abf = ws_size >= 70 * MB;
  float* H = (float*)d_out;

  if (has_abf)
    convA<<<dim3(1024), dim3(512), 0, stream>>>(A, Abf);

  for (int l = 0; l < 3; ++l) {
    const float* Wm = (const float*)d_in[2 + 3 * l];
    const float* Ws = (const float*)d_in[3 + 3 * l];
    const float* bb = (const float*)d_in[4 + 3 * l];
    const int relu = (l < 2) ? 1 : 0;
    gcn_linear<<<dim3(256), dim3(256), 0, stream>>>((l == 0) ? X : H, Wm, Ws, bb, Mt, S);
    if (has_abf)
      gcn_gemm<1><<<dim3(1024), dim3(512), 0, stream>>>(A, Abf, Mt, S, H, relu);
    else
      gcn_gemm<2><<<dim3(1024), dim3(512), 0, stream>>>(A, Abf, Mt, S, H, relu);
  }
}

// Round 7
// 147.997 us; speedup vs baseline: 1.1041x; 1.1041x over previous
//
#include <hip/hip_runtime.h>

typedef float  f32x4  __attribute__((ext_vector_type(4)));
typedef short  bf16x8 __attribute__((ext_vector_type(8)));

#define NN 2048
#define CC 64

#define WAITVM(N) asm volatile("s_waitcnt vmcnt(" #N ")" ::: "memory")
#define LGKM0     asm volatile("s_waitcnt lgkmcnt(0)" ::: "memory")

__device__ __forceinline__ unsigned short f2bf(float f) {
  union { float f; unsigned u; } v; v.f = f;
  unsigned r = v.u + 0x7fffu + ((v.u >> 16) & 1u);
  return (unsigned short)(r >> 16);
}

__device__ __forceinline__ void gll16(const void* g, void* l) {
  __builtin_amdgcn_global_load_lds(
      (const __attribute__((address_space(1))) unsigned int*)g,
      (__attribute__((address_space(3))) unsigned int*)l, 16, 0, 0);
}

// ---------------- per-layer linear: Mt = (H*Wm^T)^T bf16, S = H*Ws^T + b ----------------
__global__ __launch_bounds__(256) void gcn_linear(
    const float* __restrict__ H, const float* __restrict__ Wm,
    const float* __restrict__ Ws, const float* __restrict__ bias,
    unsigned short* __restrict__ Mt, float* __restrict__ S)
{
  const int bid = blockIdx.x;
  const int b   = bid >> 5;
  const int n0  = (bid & 31) << 6;
  const int tid = threadIdx.x;

  __shared__ float4 Hl[1024];
  __shared__ float4 Wm4[1024];
  __shared__ float4 Ws4[1024];

  const float4* Hg  = reinterpret_cast<const float4*>(H + ((size_t)b * NN + n0) * CC);
  const float4* Wmg = reinterpret_cast<const float4*>(Wm);
  const float4* Wsg = reinterpret_cast<const float4*>(Ws);
#pragma unroll
  for (int i = 0; i < 4; ++i) {
    int f = tid + 256 * i;
    Hl[f] = Hg[f];
    int o = f >> 4, c4 = f & 15;
    int slot = (o << 4) | (c4 ^ (o & 15));
    Wm4[slot] = Wmg[f];
    Ws4[slot] = Wsg[f];
  }
  __syncthreads();

  const int o = tid & 63, wv = tid >> 6;
  float accm[16], accs[16];
#pragma unroll
  for (int p = 0; p < 16; ++p) { accm[p] = 0.f; accs[p] = 0.f; }

  for (int c4 = 0; c4 < 16; ++c4) {
    int slot = (o << 4) | (c4 ^ (o & 15));
    float4 wm  = Wm4[slot];
    float4 wsv = Ws4[slot];
#pragma unroll
    for (int p = 0; p < 16; ++p) {
      float4 h = Hl[((wv << 4) + p) * 16 + c4];
      accm[p] += h.x * wm.x  + h.y * wm.y  + h.z * wm.z  + h.w * wm.w;
      accs[p] += h.x * wsv.x + h.y * wsv.y + h.z * wsv.z + h.w * wsv.w;
    }
  }

  const float bv = bias[o];
  bf16x8 m0, m1;
#pragma unroll
  for (int p = 0; p < 8; ++p) { m0[p] = (short)f2bf(accm[p]); m1[p] = (short)f2bf(accm[8 + p]); }
  unsigned short* mp = Mt + ((size_t)b * CC + o) * NN + n0 + (wv << 4);
  *reinterpret_cast<bf16x8*>(mp)     = m0;
  *reinterpret_cast<bf16x8*>(mp + 8) = m1;
#pragma unroll
  for (int p = 0; p < 16; ++p) {
    int r = n0 + (wv << 4) + p;
    S[((size_t)b * NN + r) * CC + o] = accs[p] + bv;
  }
}

// ---------------- GEMM: H = relu?(A @ M + S) ----------------
// block = 16 rows x 8 waves; wave w owns j-chunk [w*256,+256), 4 K-tiles; per-wave
// private LDS ring depth-2 via global_load_lds, counted vmcnt only (no barriers in loop).
// R7 change: DE-AFFINITIZED bid mapping — b = bid>>7 so each batch's 128 row-blocks
// spread across all 8 XCDs (was b = bid&7: whole batch pinned to one XCD).
// DT=0: fp32 A in, bf16 tiled Abf out. DT=1: bf16 tiled Abf in. DT=2: fp32 A, no store.
template<int DT>
__global__ __launch_bounds__(512) void gcn_gemm(
    const float* __restrict__ A, unsigned short* __restrict__ Abf,
    const unsigned short* __restrict__ Mt, const float* __restrict__ S,
    float* __restrict__ H, const int relu)
{
  constexpr int TILEB = (DT == 1) ? 2048 : 4096;
  __shared__ char smem[(DT == 1) ? 32768 : 65536];

  const int bid = blockIdx.x;
  const int b   = bid >> 7;         // batch (de-affinitized: row-blocks round-robin XCDs)
  const int rb  = bid & 127;
  const int n0  = rb << 4;          // 16 rows per block
  const int tid  = threadIdx.x;
  const int w    = tid >> 6;
  const int lane = tid & 63;
  const int fr   = lane & 15, g = lane >> 4;
  const int j0   = w << 8;          // 256-wide j-chunk per wave

  char* ring = smem + w * 2 * TILEB;

  const float* Ag = A + ((size_t)(b * NN + n0)) * NN + j0;
  const size_t wgid = (size_t)bid * 8 + w;
  const unsigned short* Mb = Mt + ((size_t)b * CC + fr) * NN + j0 + (g << 3);
  unsigned short* abw = Abf + wgid * 4096 + (size_t)lane * 8;  // tiled bf16-A stream

  auto issueA = [&](int t, int s) {
    if constexpr (DT == 1) {
      const unsigned short* src = Abf + wgid * 4096 + (size_t)t * 1024 + lane * 8;
      gll16(src,       ring + s * TILEB);
      gll16(src + 512, ring + s * TILEB + 1024);
    } else {
      const int rl = lane >> 4, cl = lane & 15;
#pragma unroll
      for (int q = 0; q < 4; ++q) {
        int row = (q << 2) + rl;
        int c16 = cl ^ (row & 7);               // pre-swizzled source (T21)
        gll16(Ag + (size_t)row * NN + t * 64 + c16 * 4,
              ring + s * TILEB + (q << 10));    // linear LDS dest
      }
    }
  };

  auto loadB = [&](bf16x8* Bv, int t) {
#pragma unroll
    for (int kk = 0; kk < 2; ++kk)
#pragma unroll
      for (int n = 0; n < 4; ++n)
        Bv[kk * 4 + n] = *reinterpret_cast<const bf16x8*>(
            Mb + (size_t)(n << 4) * NN + t * 64 + (kk << 5));
  };

  auto readA = [&](int s, int t, bf16x8* af) {
    if constexpr (DT == 1) {
      af[0] = *reinterpret_cast<const bf16x8*>(ring + s * TILEB + lane * 16);
      af[1] = *reinterpret_cast<const bf16x8*>(ring + s * TILEB + 1024 + lane * 16);
      LGKM0;
      (void)t;
    } else {
      const float4* sh = reinterpret_cast<const float4*>(ring + s * TILEB);
      float4 v[4];
#pragma unroll
      for (int kk = 0; kk < 2; ++kk) {
        v[2 * kk]     = sh[(fr << 4) + (((kk << 3) + (g << 1))     ^ (fr & 7))];
        v[2 * kk + 1] = sh[(fr << 4) + (((kk << 3) + (g << 1) + 1) ^ (fr & 7))];
      }
      LGKM0;
#pragma unroll
      for (int kk = 0; kk < 2; ++kk) {
        af[kk][0] = (short)f2bf(v[2 * kk].x);     af[kk][1] = (short)f2bf(v[2 * kk].y);
        af[kk][2] = (short)f2bf(v[2 * kk].z);     af[kk][3] = (short)f2bf(v[2 * kk].w);
        af[kk][4] = (short)f2bf(v[2 * kk + 1].x); af[kk][5] = (short)f2bf(v[2 * kk + 1].y);
        af[kk][6] = (short)f2bf(v[2 * kk + 1].z); af[kk][7] = (short)f2bf(v[2 * kk + 1].w);
      }
      if constexpr (DT == 0) {
        *reinterpret_cast<bf16x8*>(abw + t * 1024)       = af[0];
        *reinterpret_cast<bf16x8*>(abw + t * 1024 + 512) = af[1];
      }
    }
  };

  f32x4 acc[4];
#pragma unroll
  for (int n = 0; n < 4; ++n) acc[n] = (f32x4){0.f, 0.f, 0.f, 0.f};

  auto mfma8 = [&](bf16x8* af, bf16x8* Bv) {
#pragma unroll
    for (int kk = 0; kk < 2; ++kk)
#pragma unroll
      for (int n = 0; n < 4; ++n)
        acc[n] = __builtin_amdgcn_mfma_f32_16x16x32_bf16(af[kk], Bv[kk * 4 + n], acc[n], 0, 0, 0);
  };

  bf16x8 B0[8], B1[8], B2[8], B3[8], af[2];

  loadB(B0, 0);
  issueA(0, 0); issueA(1, 1);

  // t0: drain A0 (A1 stays in flight)
  if constexpr (DT == 1) { WAITVM(2); } else { WAITVM(4); }
  readA(0, 0, af); loadB(B1, 1); issueA(2, 0); mfma8(af, B0);

  // t1: drain A1; in flight after = {stores?, B1, A2}
  if constexpr (DT == 0) { WAITVM(14); } else if constexpr (DT == 2) { WAITVM(12); } else { WAITVM(10); }
  readA(1, 1, af); loadB(B2, 2); issueA(3, 1); mfma8(af, B1);

  // t2: drain A2
  if constexpr (DT == 0) { WAITVM(14); } else if constexpr (DT == 2) { WAITVM(12); } else { WAITVM(10); }
  readA(0, 2, af); loadB(B3, 3); mfma8(af, B2);

  // t3: drain A3
  if constexpr (DT == 0) { WAITVM(10); } else { WAITVM(8); }
  readA(1, 3, af); mfma8(af, B3);

  // ---- cross-wave reduction (alias ring memory; all gll drained) ----
  __syncthreads();
  float* red = reinterpret_cast<float*>(smem);   // [8 waves][16 rows][64 cols]
#pragma unroll
  for (int n = 0; n < 4; ++n)
#pragma unroll
    for (int r = 0; r < 4; ++r)
      red[(w << 10) + (((g << 2) + r) << 6) + (n << 4) + fr] = acc[n][r];
  __syncthreads();
  {
    const int row = tid >> 5;
    const int col = (tid & 31) << 1;
    float2 v = make_float2(0.f, 0.f);
#pragma unroll
    for (int ww = 0; ww < 8; ++ww) {
      float2 p = *reinterpret_cast<const float2*>(&red[(ww << 10) + (row << 6) + col]);
      v.x += p.x; v.y += p.y;
    }
    const size_t idx = ((size_t)b * NN + n0 + row) * CC + col;
    float2 s = *reinterpret_cast<const float2*>(&S[idx]);
    v.x += s.x; v.y += s.y;
    if (relu) { v.x = fmaxf(v.x, 0.f); v.y = fmaxf(v.y, 0.f); }
    *reinterpret_cast<float2*>(&H[idx]) = v;
  }
}

extern "C" void kernel_launch(void* const* d_in, const int* in_sizes, int n_in,
                              void* d_out, int out_size, void* d_ws, size_t ws_size,
                              hipStream_t stream)
{
  const float* X = (const float*)d_in[0];
  const float* A = (const float*)d_in[1];
  const size_t MB = 1024 * 1024;
  unsigned short* Mt  = (unsigned short*)d_ws;                      // 2 MiB
  float*          S   = (float*)((char*)d_ws + 2 * MB);             // 4 MiB
  unsigned short* Abf = (unsigned short*)((char*)d_ws + 6 * MB);    // 64 MiB tiled bf16 A
  const bool has_abf = ws_size >= 70 * MB;
  float* H = (float*)d_out;

  for (int l = 0; l < 3; ++l) {
    const float* Wm = (const float*)d_in[2 + 3 * l];
    const float* Ws = (const float*)d_in[3 + 3 * l];
    const float* bb = (const float*)d_in[4 + 3 * l];
    const int relu = (l < 2) ? 1 : 0;
    gcn_linear<<<dim3(256), dim3(256), 0, stream>>>((l == 0) ? X : H, Wm, Ws, bb, Mt, S);
    if (has_abf) {
      if (l == 0)
        gcn_gemm<0><<<dim3(1024), dim3(512), 0, stream>>>(A, Abf, Mt, S, H, relu);
      else
        gcn_gemm<1><<<dim3(1024), dim3(512), 0, stream>>>(A, Abf, Mt, S, H, relu);
    } else {
      gcn_gemm<2><<<dim3(1024), dim3(512), 0, stream>>>(A, (unsigned short*)d_ws, Mt, S, H, relu);
    }
  }
}